// Round 14
// baseline (295.356 us; speedup 1.0000x reference)
//
#include <hip/hip_runtime.h>
#include <stdint.h>

#define NNODES 50000
#define NEDGES 800000
#define DDIM 256
#define NCLS 32
#define NGRAPH 64
#define NSCANB ((NNODES + 255) / 256)
#define HISTD ((NEDGES + 2047) / 2048)   // 391 dense edge blocks (2048 edges each)
#define HISTD8 (HISTD * 8)               // x8 XCD partitions = 3128
#define CVTXB (NNODES * 64 / 256)        // 12500
#define CVTWB (2 * 256 * 512 / 256)      // 1024
#define NPXCD (NNODES / 8)               // 6250 dst nodes per XCD

typedef short bf16x8 __attribute__((ext_vector_type(8)));
typedef float f32x4 __attribute__((ext_vector_type(4)));
typedef unsigned short u16x4 __attribute__((ext_vector_type(4)));
typedef unsigned short u16x8 __attribute__((ext_vector_type(8)));

typedef __attribute__((address_space(1))) const char glb_c;
typedef __attribute__((address_space(3))) char lds_c;

// slab layout: element (row r, col c) lives at ((c>>5)*NNODES + r)*32 + (c&31)
// 8 slabs of [50000][32] bf16 (3.2 MB each, XCD-L2-resident).

__device__ __forceinline__ unsigned short f2b(float f) {
  uint32_t u = __builtin_bit_cast(uint32_t, f);
  u += 0x7FFFu + ((u >> 16) & 1u);
  return (unsigned short)(u >> 16);
}
__device__ __forceinline__ float b2f(unsigned short u) {
  return __builtin_bit_cast(float, (uint32_t)u << 16);
}
__device__ __forceinline__ float blo(uint32_t u) {
  return __builtin_bit_cast(float, u << 16);
}
__device__ __forceinline__ float bhi(uint32_t u) {
  return __builtin_bit_cast(float, u & 0xFFFF0000u);
}

__device__ __forceinline__ void gload16(const void* g, const void* l) {
  __builtin_amdgcn_global_load_lds((glb_c*)g, (lds_c*)l, 16, 0, 0);
}

// ---------------- head: dense hist (8 edges/thread, XCD-partitioned) | cvt_x | cvt_w ----------------

__global__ void k_head(const int* __restrict__ dst, int* __restrict__ cnt,
                       const float* __restrict__ x, unsigned short* __restrict__ xb,
                       const float* __restrict__ W1l, const float* __restrict__ W1r,
                       const float* __restrict__ W2l, const float* __restrict__ W2r,
                       unsigned short* __restrict__ WT1, unsigned short* __restrict__ WT2) {
  int b = blockIdx.x;
  if (b < HISTD8) {
    int xcd = b & 7;
    int base = (b >> 3) * 2048 + threadIdx.x * 8;
    if (base < NEDGES) {   // NEDGES % 8 == 0 -> all-or-nothing per thread
      int4 d0 = *(const int4*)(dst + base);
      int4 d1 = *(const int4*)(dst + base + 4);
      int lo = xcd * NPXCD;
      int dd[8] = {d0.x, d0.y, d0.z, d0.w, d1.x, d1.y, d1.z, d1.w};
#pragma unroll
      for (int j = 0; j < 8; ++j)
        if ((unsigned)(dd[j] - lo) < (unsigned)NPXCD) atomicAdd(&cnt[dd[j]], 1);
    }
  } else if (b < HISTD8 + CVTXB) {
    int i = (b - HISTD8) * 256 + threadIdx.x;  // [0, NNODES*64), 4 cols/thread
    int r = i >> 6, c4 = i & 63;
    float4 v = *(const float4*)(x + (size_t)r * DDIM + c4 * 4);
    u16x4 o;
    o.x = f2b(v.x); o.y = f2b(v.y); o.z = f2b(v.z); o.w = f2b(v.w);
    int slab = c4 >> 3, seg = c4 & 7;
    *(u16x4*)(xb + ((size_t)slab * NNODES + r) * 32 + seg * 4) = o;
  } else {
    int idx = (b - HISTD8 - CVTXB) * 256 + threadIdx.x;  // 2*256*512
    int which = idx >> 17;
    int id2 = idx & 131071;
    int n = id2 >> 9, k = id2 & 511;
    const float* Wl = which ? W2l : W1l;
    const float* Wr = which ? W2r : W1r;
    unsigned short* WT = which ? WT2 : WT1;
    float v = (k < 256) ? Wl[k * 256 + n] : Wr[(k - 256) * 256 + n];
    WT[id2] = f2b(v);
  }
}

// ---------------- CSR scan ----------------

__global__ void k_scan1(const int* __restrict__ cnt, int* __restrict__ bsum) {
  int b = blockIdx.x;
  int i = b * 256 + threadIdx.x;
  int lane = threadIdx.x & 63, wid = threadIdx.x >> 6;
  int v = (i < NNODES) ? cnt[i] : 0;
#pragma unroll
  for (int o = 1; o < 64; o <<= 1) v += __shfl_xor(v, o, 64);
  __shared__ int ws[4];
  if (lane == 0) ws[wid] = v;
  __syncthreads();
  if (threadIdx.x == 0) bsum[b] = ws[0] + ws[1] + ws[2] + ws[3];
}

__global__ void k_scan2(const int* __restrict__ bsum, int* __restrict__ boffs) {
  int tid = threadIdx.x, lane = tid & 63, wid = tid >> 6;
  int v = (tid < NSCANB) ? bsum[tid] : 0;
  int s = v;
#pragma unroll
  for (int o = 1; o < 64; o <<= 1) {
    int t = __shfl_up(s, o, 64);
    if (lane >= o) s += t;
  }
  __shared__ int ws[4];
  if (lane == 63) ws[wid] = s;
  __syncthreads();
  int add = 0;
  for (int w = 0; w < wid; ++w) add += ws[w];
  if (tid < NSCANB) boffs[tid] = s + add - v;  // exclusive
}

// scan3 + zero(gsum) + graph counts, fused via block partitioning
__global__ void k_scan3(const int* __restrict__ cnt, const int* __restrict__ boffs,
                        int* __restrict__ rowptr, int* __restrict__ cursor,
                        float* __restrict__ gsum, const int* __restrict__ batch,
                        int* __restrict__ gcnt) {
  int b = blockIdx.x;
  if (b < NSCANB) {
    int i = b * 256 + threadIdx.x;
    int lane = threadIdx.x & 63, wid = threadIdx.x >> 6;
    int v = (i < NNODES) ? cnt[i] : 0;
    int s = v;
#pragma unroll
    for (int o = 1; o < 64; o <<= 1) {
      int t = __shfl_up(s, o, 64);
      if (lane >= o) s += t;
    }
    __shared__ int ws[4];
    if (lane == 63) ws[wid] = s;
    __syncthreads();
    int add = boffs[b];
    for (int w = 0; w < wid; ++w) add += ws[w];
    int incl = s + add;
    if (i < NNODES) {
      rowptr[i + 1] = incl;
      cursor[i] = incl - v;
    }
    if (b == 0 && threadIdx.x == 0) rowptr[0] = 0;
  } else if (b == NSCANB) {
    for (int i = threadIdx.x; i < NGRAPH * DDIM; i += 256) gsum[i] = 0.f;
  } else {
    int g = threadIdx.x;
    if (g < NGRAPH) {
      int lo = 0, hi = NNODES;
      while (lo < hi) { int m = (lo + hi) >> 1; if (batch[m] < g) lo = m + 1; else hi = m; }
      int lo2 = lo, hi2 = NNODES;
      while (lo2 < hi2) { int m = (lo2 + hi2) >> 1; if (batch[m] < g + 1) lo2 = m + 1; else hi2 = m; }
      gcnt[g] = lo2 - lo;
    }
  }
}

// ---------------- fill: dense (8 edges/thread), XCD-partitioned ----------------

__global__ void k_fill(const int* __restrict__ src, const int* __restrict__ dst,
                       int* __restrict__ cursor, int* __restrict__ col) {
  int b = blockIdx.x;
  int xcd = b & 7;
  int base = (b >> 3) * 2048 + threadIdx.x * 8;
  if (base < NEDGES) {
    int4 d0 = *(const int4*)(dst + base);
    int4 d1 = *(const int4*)(dst + base + 4);
    int lo = xcd * NPXCD;
    int dd[8] = {d0.x, d0.y, d0.z, d0.w, d1.x, d1.y, d1.z, d1.w};
#pragma unroll
    for (int j = 0; j < 8; ++j) {
      if ((unsigned)(dd[j] - lo) < (unsigned)NPXCD) {
        int p = atomicAdd(&cursor[dd[j]], 1);
        col[p] = src[base + j];
      }
    }
  }
}

// ---------------- aggregation: slab gather, 16B/lane, 8x MLP (R10 proven) ----------------

__global__ void k_agg(const unsigned short* __restrict__ feat,
                      const int* __restrict__ rowptr, const int* __restrict__ col,
                      unsigned short* __restrict__ out) {
  int g = blockIdx.x & 7;          // slab == XCD
  int nb = blockIdx.x >> 3;        // 64 nodes per block
  int wv = threadIdx.x >> 6, lane = threadIdx.x & 63;
  int ns = lane >> 2;              // node slot 0..15 within wave
  int seg = lane & 3;              // 16B segment within 64B slab row
  int node = nb * 64 + wv * 16 + ns;
  bool valid = node < NNODES;
  int nn = valid ? node : NNODES - 1;
  int s = rowptr[nn], e = rowptr[nn + 1];
  if (!valid) e = s;
  const unsigned short* slabp = feat + (size_t)g * NNODES * 32 + seg * 8;
  float a[8] = {0.f}, bb[8] = {0.f};
  int last = e - 1;
  for (int i = s; i < e; i += 8) {
    uint4 vv[8];
#pragma unroll
    for (int j = 0; j < 8; ++j) {
      int idx = i + j;
      int cidx = (idx <= last) ? idx : last;
      int ce = col[cidx];
      uint4 r = *(const uint4*)(slabp + (size_t)ce * 32);
      if (idx > last) { r.x = 0u; r.y = 0u; r.z = 0u; r.w = 0u; }
      vv[j] = r;
    }
#pragma unroll
    for (int j = 0; j < 8; j += 2) {
      a[0] += blo(vv[j].x); a[1] += bhi(vv[j].x);
      a[2] += blo(vv[j].y); a[3] += bhi(vv[j].y);
      a[4] += blo(vv[j].z); a[5] += bhi(vv[j].z);
      a[6] += blo(vv[j].w); a[7] += bhi(vv[j].w);
      bb[0] += blo(vv[j + 1].x); bb[1] += bhi(vv[j + 1].x);
      bb[2] += blo(vv[j + 1].y); bb[3] += bhi(vv[j + 1].y);
      bb[4] += blo(vv[j + 1].z); bb[5] += bhi(vv[j + 1].z);
      bb[6] += blo(vv[j + 1].w); bb[7] += bhi(vv[j + 1].w);
    }
  }
  if (valid) {
    float inv = (e > s) ? 1.f / (float)(e - s) : 0.f;
    u16x8 o;
#pragma unroll
    for (int j = 0; j < 8; ++j) o[j] = f2b((a[j] + bb[j]) * inv);
    unsigned short* op = out + ((size_t)g * NNODES + node) * 32 + seg * 8;
    __builtin_nontemporal_store(o, (u16x8*)op);
  }
}

// ---------------- GEMM: 128x256 tile (single N pass), 512 thr / 8 waves ----------------

__global__ void k_gemm(const unsigned short* __restrict__ Aagg,
                       const unsigned short* __restrict__ Aroot,
                       const unsigned short* __restrict__ WT,   // [256][512]
                       const float* __restrict__ bias,          // [256]
                       unsigned short* __restrict__ out) {      // slab layout
  __shared__ unsigned short As[128 * 32];
  __shared__ unsigned short Bs[256 * 32];
  int m0 = blockIdx.x * 128;
  int tid = threadIdx.x, lane = tid & 63, wv = tid >> 6;
  int wm = wv >> 1, wn = wv & 1;   // 4 x 2 wave grid; wave = 32 rows x 128 cols

  f32x4 acc[2][8];
#pragma unroll
  for (int m = 0; m < 2; ++m)
#pragma unroll
    for (int n = 0; n < 8; ++n) acc[m][n] = (f32x4)0.f;

  for (int kt = 0; kt < 16; ++kt) {
    int k = kt * 32;
    const unsigned short* Abase = (kt < 8) ? Aagg : Aroot;
    int slab = kt & 7;
    const unsigned short* Aslab = Abase + (size_t)slab * NNODES * 32;
    {
      int row = tid >> 2, sg = tid & 3;
      int gr = m0 + row;
      if (gr >= NNODES) gr = NNODES - 1;
      const unsigned short* sp = Aslab + (size_t)gr * 32 + sg * 8;
      gload16(sp, (const char*)As + (wv * 64) * 16);
    }
#pragma unroll
    for (int p = 0; p < 2; ++p) {
      int idx = p * 512 + tid;
      int row = idx >> 2, sg = idx & 3;
      const unsigned short* sp = WT + (size_t)row * 512 + k + sg * 8;
      gload16(sp, (const char*)Bs + (p * 512 + wv * 64) * 16);
    }
    __syncthreads();

    bf16x8 af[2], bfr[8];
    int kb = (lane >> 4) * 8;
    int rA = wm * 32 + (lane & 15);
    int rB = wn * 128 + (lane & 15);
#pragma unroll
    for (int m = 0; m < 2; ++m) af[m] = *(const bf16x8*)&As[(rA + m * 16) * 32 + kb];
#pragma unroll
    for (int n = 0; n < 8; ++n) bfr[n] = *(const bf16x8*)&Bs[(rB + n * 16) * 32 + kb];
#pragma unroll
    for (int m = 0; m < 2; ++m)
#pragma unroll
      for (int n = 0; n < 8; ++n)
        acc[m][n] = __builtin_amdgcn_mfma_f32_16x16x32_bf16(af[m], bfr[n], acc[m][n], 0, 0, 0);
    __syncthreads();
  }

  int rbase = m0 + wm * 32 + (lane >> 4) * 4;
  int cb = wn * 128 + (lane & 15);
#pragma unroll
  for (int n = 0; n < 8; ++n) {
    int cc = cb + n * 16;
    float bv = bias[cc];
    size_t sbase = (size_t)(cc >> 5) * NNODES * 32 + (cc & 31);
#pragma unroll
    for (int m = 0; m < 2; ++m) {
#pragma unroll
      for (int j = 0; j < 4; ++j) {
        int r = rbase + m * 16 + j;
        if (r < NNODES) {
          float v = acc[m][n][j] + bv;
          v = fmaxf(v, 0.f);
          out[sbase + (size_t)r * 32] = f2b(v);
        }
      }
    }
  }
}

// ---------------- pool + classifier ----------------

#define GSUM_WAVES 1024
__global__ void k_gsum(const unsigned short* __restrict__ h2,  // slab layout
                       const int* __restrict__ batch,
                       float* __restrict__ gsum) {  // [NGRAPH][DDIM], pre-zeroed
  int wave = (blockIdx.x * blockDim.x + threadIdx.x) >> 6;
  int lane = threadIdx.x & 63;
  const int per = (NNODES + GSUM_WAVES - 1) / GSUM_WAVES;
  int r0 = wave * per;
  int r1 = r0 + per; if (r1 > NNODES) r1 = NNODES;
  if (r0 >= r1) return;
  int slab = lane >> 3, seg = lane & 7;
  int cb = slab * 32 + seg * 4;
  const unsigned short* sp = h2 + (size_t)slab * NNODES * 32 + seg * 4;
  float a0 = 0.f, a1 = 0.f, a2 = 0.f, a3 = 0.f;
  int cur = batch[r0];
  for (int r = r0; r < r1; ++r) {
    int g = batch[r];
    if (g != cur) {
      float* gp = gsum + cur * DDIM + cb;
      atomicAdd(gp + 0, a0); atomicAdd(gp + 1, a1);
      atomicAdd(gp + 2, a2); atomicAdd(gp + 3, a3);
      a0 = a1 = a2 = a3 = 0.f;
      cur = g;
    }
    u16x4 v = *(const u16x4*)(sp + (size_t)r * 32);
    a0 += b2f(v.x); a1 += b2f(v.y); a2 += b2f(v.z); a3 += b2f(v.w);
  }
  float* gp = gsum + cur * DDIM + cb;
  atomicAdd(gp + 0, a0); atomicAdd(gp + 1, a1);
  atomicAdd(gp + 2, a2); atomicAdd(gp + 3, a3);
}

__global__ void k_cls(const float* __restrict__ gsum, const int* __restrict__ cnt,
                      const float* __restrict__ Wc, const float* __restrict__ bc,
                      float* __restrict__ out) {
  int g = blockIdx.x;
  __shared__ float colmean[DDIM];
  int c = threadIdx.x;
  int n = cnt[g];
  float inv = (n > 0) ? 1.f / (float)n : 0.f;
  colmean[c] = gsum[g * DDIM + c] * inv;
  __syncthreads();
  if (c < NCLS) {
    float o = bc[c];
#pragma unroll 4
    for (int k = 0; k < DDIM; ++k) o += colmean[k] * Wc[k * NCLS + c];
    out[g * NCLS + c] = o;
  }
}

// ---------------- launch ----------------

extern "C" void kernel_launch(void* const* d_in, const int* in_sizes, int n_in,
                              void* d_out, int out_size, void* d_ws, size_t ws_size,
                              hipStream_t stream) {
  const float* x    = (const float*)d_in[0];
  const int* eidx   = (const int*)d_in[1];
  const int* batch  = (const int*)d_in[2];
  const float* W1l  = (const float*)d_in[3];
  const float* b1   = (const float*)d_in[4];
  const float* W1r  = (const float*)d_in[5];
  const float* W2l  = (const float*)d_in[6];
  const float* b2   = (const float*)d_in[7];
  const float* W2r  = (const float*)d_in[8];
  const float* Wc   = (const float*)d_in[9];
  const float* bc   = (const float*)d_in[10];
  float* out = (float*)d_out;

  const int* esrc = eidx;
  const int* edst = eidx + NEDGES;

  char* w = (char*)d_ws;
  size_t off = 0;
  auto alloc = [&](size_t bytes) -> char* {
    char* p = w + off;
    off = (off + bytes + 255) & ~(size_t)255;
    return p;
  };
  int* rowptr = (int*)alloc((NNODES + 1) * sizeof(int));
  int* cnt    = (int*)alloc(NNODES * sizeof(int));
  int* cursor = (int*)alloc(NNODES * sizeof(int));
  int* col    = (int*)alloc(NEDGES * sizeof(int));
  unsigned short* xb   = (unsigned short*)alloc((size_t)NNODES * DDIM * 2);
  unsigned short* h1b  = (unsigned short*)alloc((size_t)NNODES * DDIM * 2);
  unsigned short* aggb = (unsigned short*)alloc((size_t)NNODES * DDIM * 2);
  unsigned short* WT1  = (unsigned short*)alloc(512 * 256 * 2);
  unsigned short* WT2  = (unsigned short*)alloc(512 * 256 * 2);
  float* gsum = (float*)alloc(NGRAPH * DDIM * sizeof(float));
  int* gcnt   = (int*)alloc(NGRAPH * sizeof(int));
  int* bsum   = (int*)alloc(NSCANB * sizeof(int));
  int* boffs  = (int*)alloc(NSCANB * sizeof(int));

  // head: hist (dense, partitioned) || cvt_x || cvt_w
  hipMemsetAsync(cnt, 0, NNODES * sizeof(int), stream);
  k_head<<<HISTD8 + CVTXB + CVTWB, 256, 0, stream>>>(edst, cnt, x, xb,
                                                     W1l, W1r, W2l, W2r, WT1, WT2);
  k_scan1<<<NSCANB, 256, 0, stream>>>(cnt, bsum);
  k_scan2<<<1, 256, 0, stream>>>(bsum, boffs);
  k_scan3<<<NSCANB + 2, 256, 0, stream>>>(cnt, boffs, rowptr, cursor,
                                          gsum, batch, gcnt);
  k_fill<<<HISTD8, 256, 0, stream>>>(esrc, edst, cursor, col);

  int ggrid = (NNODES + 127) / 128;
  int agg_grid = ((NNODES + 63) / 64) * 8;

  // layer 1
  k_agg<<<agg_grid, 256, 0, stream>>>(xb, rowptr, col, aggb);
  k_gemm<<<ggrid, 512, 0, stream>>>(aggb, xb, WT1, b1, h1b);

  // layer 2
  k_agg<<<agg_grid, 256, 0, stream>>>(h1b, rowptr, col, aggb);
  k_gemm<<<ggrid, 512, 0, stream>>>(aggb, h1b, WT2, b2, xb);

  // pool + classifier
  k_gsum<<<GSUM_WAVES / 4, 256, 0, stream>>>(xb, batch, gsum);
  k_cls<<<NGRAPH, 256, 0, stream>>>(gsum, gcnt, Wc, bc, out);
}

// Round 15
// 290.408 us; speedup vs baseline: 1.0170x; 1.0170x over previous
//
#include <hip/hip_runtime.h>
#include <stdint.h>

#define NNODES 50000
#define NEDGES 800000
#define DDIM 256
#define NCLS 32
#define NGRAPH 64
#define NSCANB ((NNODES + 255) / 256)
#define HISTB ((NEDGES + 255) / 256)
#define HISTB8 (HISTB * 8)
#define CVTXB (NNODES * 64 / 256)    // 12500
#define CVTWB (2 * 256 * 512 / 256)  // 1024
#define NPXCD (NNODES / 8)           // 6250 dst nodes per XCD

typedef short bf16x8 __attribute__((ext_vector_type(8)));
typedef float f32x4 __attribute__((ext_vector_type(4)));
typedef unsigned short u16x4 __attribute__((ext_vector_type(4)));
typedef unsigned short u16x8 __attribute__((ext_vector_type(8)));

typedef __attribute__((address_space(1))) const char glb_c;
typedef __attribute__((address_space(3))) char lds_c;

// slab layout: element (row r, col c) lives at ((c>>5)*NNODES + r)*32 + (c&31)
// 8 slabs of [50000][32] bf16 (3.2 MB each, XCD-L2-resident).
// col[] stores PRESCALED offsets: src_node * 32 (ushort elements).

__device__ __forceinline__ unsigned short f2b(float f) {
  uint32_t u = __builtin_bit_cast(uint32_t, f);
  u += 0x7FFFu + ((u >> 16) & 1u);
  return (unsigned short)(u >> 16);
}
__device__ __forceinline__ float b2f(unsigned short u) {
  return __builtin_bit_cast(float, (uint32_t)u << 16);
}
__device__ __forceinline__ float blo(uint32_t u) {
  return __builtin_bit_cast(float, u << 16);
}
__device__ __forceinline__ float bhi(uint32_t u) {
  return __builtin_bit_cast(float, u & 0xFFFF0000u);
}

__device__ __forceinline__ void gload16(const void* g, const void* l) {
  __builtin_amdgcn_global_load_lds((glb_c*)g, (lds_c*)l, 16, 0, 0);
}

// ---------------- CSR build: XCD-partitioned hist ----------------

__global__ void k_hist(const int* __restrict__ dst, int* __restrict__ cnt) {
  int b = blockIdx.x;
  int xcd = b & 7;
  int e = (b >> 3) * 256 + threadIdx.x;
  if (e < NEDGES) {
    int d = dst[e];
    if ((unsigned)(d - xcd * NPXCD) < (unsigned)NPXCD) atomicAdd(&cnt[d], 1);
  }
}

__global__ void k_scan1(const int* __restrict__ cnt, int* __restrict__ bsum) {
  int b = blockIdx.x;
  int i = b * 256 + threadIdx.x;
  int lane = threadIdx.x & 63, wid = threadIdx.x >> 6;
  int v = (i < NNODES) ? cnt[i] : 0;
#pragma unroll
  for (int o = 1; o < 64; o <<= 1) v += __shfl_xor(v, o, 64);
  __shared__ int ws[4];
  if (lane == 0) ws[wid] = v;
  __syncthreads();
  if (threadIdx.x == 0) bsum[b] = ws[0] + ws[1] + ws[2] + ws[3];
}

__global__ void k_scan2(const int* __restrict__ bsum, int* __restrict__ boffs) {
  int tid = threadIdx.x, lane = tid & 63, wid = tid >> 6;
  int v = (tid < NSCANB) ? bsum[tid] : 0;
  int s = v;
#pragma unroll
  for (int o = 1; o < 64; o <<= 1) {
    int t = __shfl_up(s, o, 64);
    if (lane >= o) s += t;
  }
  __shared__ int ws[4];
  if (lane == 63) ws[wid] = s;
  __syncthreads();
  int add = 0;
  for (int w = 0; w < wid; ++w) add += ws[w];
  if (tid < NSCANB) boffs[tid] = s + add - v;  // exclusive
}

// scan3 + zero(gsum) + graph counts, fused via block partitioning
__global__ void k_scan3(const int* __restrict__ cnt, const int* __restrict__ boffs,
                        int* __restrict__ rowptr, int* __restrict__ cursor,
                        float* __restrict__ gsum, const int* __restrict__ batch,
                        int* __restrict__ gcnt) {
  int b = blockIdx.x;
  if (b < NSCANB) {
    int i = b * 256 + threadIdx.x;
    int lane = threadIdx.x & 63, wid = threadIdx.x >> 6;
    int v = (i < NNODES) ? cnt[i] : 0;
    int s = v;
#pragma unroll
    for (int o = 1; o < 64; o <<= 1) {
      int t = __shfl_up(s, o, 64);
      if (lane >= o) s += t;
    }
    __shared__ int ws[4];
    if (lane == 63) ws[wid] = s;
    __syncthreads();
    int add = boffs[b];
    for (int w = 0; w < wid; ++w) add += ws[w];
    int incl = s + add;
    if (i < NNODES) {
      rowptr[i + 1] = incl;
      cursor[i] = incl - v;
    }
    if (b == 0 && threadIdx.x == 0) rowptr[0] = 0;
  } else if (b == NSCANB) {
    for (int i = threadIdx.x; i < NGRAPH * DDIM; i += 256) gsum[i] = 0.f;
  } else {
    int g = threadIdx.x;
    if (g < NGRAPH) {
      int lo = 0, hi = NNODES;
      while (lo < hi) { int m = (lo + hi) >> 1; if (batch[m] < g) lo = m + 1; else hi = m; }
      int lo2 = lo, hi2 = NNODES;
      while (lo2 < hi2) { int m = (lo2 + hi2) >> 1; if (batch[m] < g + 1) lo2 = m + 1; else hi2 = m; }
      gcnt[g] = lo2 - lo;
    }
  }
}

// ---------------- fused: fill (XCD-partitioned, prescaled col) | cvt_x | cvt_w ----------------

__global__ void k_fillcvt(const int* __restrict__ src, const int* __restrict__ dst,
                          int* __restrict__ cursor, int* __restrict__ col,
                          const float* __restrict__ x, unsigned short* __restrict__ xb,
                          const float* __restrict__ W1l, const float* __restrict__ W1r,
                          const float* __restrict__ W2l, const float* __restrict__ W2r,
                          unsigned short* __restrict__ WT1, unsigned short* __restrict__ WT2) {
  int b = blockIdx.x;
  if (b < HISTB8) {
    int xcd = b & 7;
    int e = (b >> 3) * 256 + threadIdx.x;
    if (e < NEDGES) {
      int d = dst[e];
      if ((unsigned)(d - xcd * NPXCD) < (unsigned)NPXCD) {
        int p = atomicAdd(&cursor[d], 1);
        col[p] = src[e] * 32;   // prescaled: ushort-element offset of slab row
      }
    }
  } else if (b < HISTB8 + CVTXB) {
    int i = (b - HISTB8) * 256 + threadIdx.x;  // [0, NNODES*64), 4 cols/thread
    int r = i >> 6, c4 = i & 63;
    float4 v = *(const float4*)(x + (size_t)r * DDIM + c4 * 4);
    u16x4 o;
    o.x = f2b(v.x); o.y = f2b(v.y); o.z = f2b(v.z); o.w = f2b(v.w);
    int slab = c4 >> 3, seg = c4 & 7;
    *(u16x4*)(xb + ((size_t)slab * NNODES + r) * 32 + seg * 4) = o;
  } else {
    int idx = (b - HISTB8 - CVTXB) * 256 + threadIdx.x;  // 2*256*512
    int which = idx >> 17;
    int id2 = idx & 131071;
    int n = id2 >> 9, k = id2 & 511;
    const float* Wl = which ? W2l : W1l;
    const float* Wr = which ? W2r : W1r;
    unsigned short* WT = which ? WT2 : WT1;
    float v = (k < 256) ? Wl[k * 256 + n] : Wr[(k - 256) * 256 + n];
    WT[id2] = f2b(v);
  }
}

// ---------------- aggregation: slab gather, 16B/lane ----------------
// Unclamped 8-deep body (8 independent loads batched before the waitcnt)
// + single clamped tail chunk. col[] holds prescaled offsets (node*32).

__global__ void k_agg(const unsigned short* __restrict__ feat,
                      const int* __restrict__ rowptr, const int* __restrict__ col,
                      unsigned short* __restrict__ out) {
  int g = blockIdx.x & 7;          // slab == XCD
  int nb = blockIdx.x >> 3;        // 64 nodes per block
  int wv = threadIdx.x >> 6, lane = threadIdx.x & 63;
  int ns = lane >> 2;              // node slot 0..15 within wave
  int seg = lane & 3;              // 16B segment within 64B slab row
  int node = nb * 64 + wv * 16 + ns;
  bool valid = node < NNODES;
  int nn = valid ? node : NNODES - 1;
  int s = rowptr[nn], e = rowptr[nn + 1];
  if (!valid) e = s;
  const unsigned short* slabp = feat + (size_t)g * NNODES * 32 + seg * 8;
  float a[8] = {0.f}, bb[8] = {0.f};
  int i = s;
  // body: full 8-edge chunks, unconditional loads
  for (; i + 8 <= e; i += 8) {
    uint4 vv[8];
#pragma unroll
    for (int j = 0; j < 8; ++j) {
      int ce = col[i + j];
      vv[j] = *(const uint4*)(slabp + (size_t)ce);
    }
#pragma unroll
    for (int j = 0; j < 8; j += 2) {
      a[0] += blo(vv[j].x); a[1] += bhi(vv[j].x);
      a[2] += blo(vv[j].y); a[3] += bhi(vv[j].y);
      a[4] += blo(vv[j].z); a[5] += bhi(vv[j].z);
      a[6] += blo(vv[j].w); a[7] += bhi(vv[j].w);
      bb[0] += blo(vv[j + 1].x); bb[1] += bhi(vv[j + 1].x);
      bb[2] += blo(vv[j + 1].y); bb[3] += bhi(vv[j + 1].y);
      bb[4] += blo(vv[j + 1].z); bb[5] += bhi(vv[j + 1].z);
      bb[6] += blo(vv[j + 1].w); bb[7] += bhi(vv[j + 1].w);
    }
  }
  // tail: one clamped chunk
  if (i < e) {
    int last = e - 1;
    uint4 vv[8];
#pragma unroll
    for (int j = 0; j < 8; ++j) {
      int idx = i + j;
      int cidx = (idx <= last) ? idx : last;
      int ce = col[cidx];
      uint4 r = *(const uint4*)(slabp + (size_t)ce);
      if (idx > last) { r.x = 0u; r.y = 0u; r.z = 0u; r.w = 0u; }
      vv[j] = r;
    }
#pragma unroll
    for (int j = 0; j < 8; j += 2) {
      a[0] += blo(vv[j].x); a[1] += bhi(vv[j].x);
      a[2] += blo(vv[j].y); a[3] += bhi(vv[j].y);
      a[4] += blo(vv[j].z); a[5] += bhi(vv[j].z);
      a[6] += blo(vv[j].w); a[7] += bhi(vv[j].w);
      bb[0] += blo(vv[j + 1].x); bb[1] += bhi(vv[j + 1].x);
      bb[2] += blo(vv[j + 1].y); bb[3] += bhi(vv[j + 1].y);
      bb[4] += blo(vv[j + 1].z); bb[5] += bhi(vv[j + 1].z);
      bb[6] += blo(vv[j + 1].w); bb[7] += bhi(vv[j + 1].w);
    }
  }
  if (valid) {
    float inv = (e > s) ? 1.f / (float)(e - s) : 0.f;
    u16x8 o;
#pragma unroll
    for (int j = 0; j < 8; ++j) o[j] = f2b((a[j] + bb[j]) * inv);
    unsigned short* op = out + ((size_t)g * NNODES + node) * 32 + seg * 8;
    __builtin_nontemporal_store(o, (u16x8*)op);
  }
}

// ---------------- GEMM: 128x256 tile (single N pass), 512 thr / 8 waves ----------------

__global__ void k_gemm(const unsigned short* __restrict__ Aagg,
                       const unsigned short* __restrict__ Aroot,
                       const unsigned short* __restrict__ WT,   // [256][512]
                       const float* __restrict__ bias,          // [256]
                       unsigned short* __restrict__ out) {      // slab layout
  __shared__ unsigned short As[128 * 32];
  __shared__ unsigned short Bs[256 * 32];
  int m0 = blockIdx.x * 128;
  int tid = threadIdx.x, lane = tid & 63, wv = tid >> 6;
  int wm = wv >> 1, wn = wv & 1;   // 4 x 2 wave grid; wave = 32 rows x 128 cols

  f32x4 acc[2][8];
#pragma unroll
  for (int m = 0; m < 2; ++m)
#pragma unroll
    for (int n = 0; n < 8; ++n) acc[m][n] = (f32x4)0.f;

  for (int kt = 0; kt < 16; ++kt) {
    int k = kt * 32;
    const unsigned short* Abase = (kt < 8) ? Aagg : Aroot;
    int slab = kt & 7;
    const unsigned short* Aslab = Abase + (size_t)slab * NNODES * 32;
    {
      int row = tid >> 2, sg = tid & 3;
      int gr = m0 + row;
      if (gr >= NNODES) gr = NNODES - 1;
      const unsigned short* sp = Aslab + (size_t)gr * 32 + sg * 8;
      gload16(sp, (const char*)As + (wv * 64) * 16);
    }
#pragma unroll
    for (int p = 0; p < 2; ++p) {
      int idx = p * 512 + tid;
      int row = idx >> 2, sg = idx & 3;
      const unsigned short* sp = WT + (size_t)row * 512 + k + sg * 8;
      gload16(sp, (const char*)Bs + (p * 512 + wv * 64) * 16);
    }
    __syncthreads();

    bf16x8 af[2], bfr[8];
    int kb = (lane >> 4) * 8;
    int rA = wm * 32 + (lane & 15);
    int rB = wn * 128 + (lane & 15);
#pragma unroll
    for (int m = 0; m < 2; ++m) af[m] = *(const bf16x8*)&As[(rA + m * 16) * 32 + kb];
#pragma unroll
    for (int n = 0; n < 8; ++n) bfr[n] = *(const bf16x8*)&Bs[(rB + n * 16) * 32 + kb];
#pragma unroll
    for (int m = 0; m < 2; ++m)
#pragma unroll
      for (int n = 0; n < 8; ++n)
        acc[m][n] = __builtin_amdgcn_mfma_f32_16x16x32_bf16(af[m], bfr[n], acc[m][n], 0, 0, 0);
    __syncthreads();
  }

  int rbase = m0 + wm * 32 + (lane >> 4) * 4;
  int cb = wn * 128 + (lane & 15);
#pragma unroll
  for (int n = 0; n < 8; ++n) {
    int cc = cb + n * 16;
    float bv = bias[cc];
    size_t sbase = (size_t)(cc >> 5) * NNODES * 32 + (cc & 31);
#pragma unroll
    for (int m = 0; m < 2; ++m) {
#pragma unroll
      for (int j = 0; j < 4; ++j) {
        int r = rbase + m * 16 + j;
        if (r < NNODES) {
          float v = acc[m][n][j] + bv;
          v = fmaxf(v, 0.f);
          out[sbase + (size_t)r * 32] = f2b(v);
        }
      }
    }
  }
}

// ---------------- pool + classifier ----------------

#define GSUM_WAVES 1024
__global__ void k_gsum(const unsigned short* __restrict__ h2,  // slab layout
                       const int* __restrict__ batch,
                       float* __restrict__ gsum) {  // [NGRAPH][DDIM], pre-zeroed
  int wave = (blockIdx.x * blockDim.x + threadIdx.x) >> 6;
  int lane = threadIdx.x & 63;
  const int per = (NNODES + GSUM_WAVES - 1) / GSUM_WAVES;
  int r0 = wave * per;
  int r1 = r0 + per; if (r1 > NNODES) r1 = NNODES;
  if (r0 >= r1) return;
  int slab = lane >> 3, seg = lane & 7;
  int cb = slab * 32 + seg * 4;
  const unsigned short* sp = h2 + (size_t)slab * NNODES * 32 + seg * 4;
  float a0 = 0.f, a1 = 0.f, a2 = 0.f, a3 = 0.f;
  int cur = batch[r0];
  for (int r = r0; r < r1; ++r) {
    int g = batch[r];
    if (g != cur) {
      float* gp = gsum + cur * DDIM + cb;
      atomicAdd(gp + 0, a0); atomicAdd(gp + 1, a1);
      atomicAdd(gp + 2, a2); atomicAdd(gp + 3, a3);
      a0 = a1 = a2 = a3 = 0.f;
      cur = g;
    }
    u16x4 v = *(const u16x4*)(sp + (size_t)r * 32);
    a0 += b2f(v.x); a1 += b2f(v.y); a2 += b2f(v.z); a3 += b2f(v.w);
  }
  float* gp = gsum + cur * DDIM + cb;
  atomicAdd(gp + 0, a0); atomicAdd(gp + 1, a1);
  atomicAdd(gp + 2, a2); atomicAdd(gp + 3, a3);
}

__global__ void k_cls(const float* __restrict__ gsum, const int* __restrict__ cnt,
                      const float* __restrict__ Wc, const float* __restrict__ bc,
                      float* __restrict__ out) {
  int g = blockIdx.x;
  __shared__ float colmean[DDIM];
  int c = threadIdx.x;
  int n = cnt[g];
  float inv = (n > 0) ? 1.f / (float)n : 0.f;
  colmean[c] = gsum[g * DDIM + c] * inv;
  __syncthreads();
  if (c < NCLS) {
    float o = bc[c];
#pragma unroll 4
    for (int k = 0; k < DDIM; ++k) o += colmean[k] * Wc[k * NCLS + c];
    out[g * NCLS + c] = o;
  }
}

// ---------------- launch ----------------

extern "C" void kernel_launch(void* const* d_in, const int* in_sizes, int n_in,
                              void* d_out, int out_size, void* d_ws, size_t ws_size,
                              hipStream_t stream) {
  const float* x    = (const float*)d_in[0];
  const int* eidx   = (const int*)d_in[1];
  const int* batch  = (const int*)d_in[2];
  const float* W1l  = (const float*)d_in[3];
  const float* b1   = (const float*)d_in[4];
  const float* W1r  = (const float*)d_in[5];
  const float* W2l  = (const float*)d_in[6];
  const float* b2   = (const float*)d_in[7];
  const float* W2r  = (const float*)d_in[8];
  const float* Wc   = (const float*)d_in[9];
  const float* bc   = (const float*)d_in[10];
  float* out = (float*)d_out;

  const int* esrc = eidx;
  const int* edst = eidx + NEDGES;

  char* w = (char*)d_ws;
  size_t off = 0;
  auto alloc = [&](size_t bytes) -> char* {
    char* p = w + off;
    off = (off + bytes + 255) & ~(size_t)255;
    return p;
  };
  int* rowptr = (int*)alloc((NNODES + 1) * sizeof(int));
  int* cnt    = (int*)alloc(NNODES * sizeof(int));
  int* cursor = (int*)alloc(NNODES * sizeof(int));
  int* col    = (int*)alloc(NEDGES * sizeof(int));
  unsigned short* xb   = (unsigned short*)alloc((size_t)NNODES * DDIM * 2);
  unsigned short* h1b  = (unsigned short*)alloc((size_t)NNODES * DDIM * 2);
  unsigned short* aggb = (unsigned short*)alloc((size_t)NNODES * DDIM * 2);
  unsigned short* WT1  = (unsigned short*)alloc(512 * 256 * 2);
  unsigned short* WT2  = (unsigned short*)alloc(512 * 256 * 2);
  float* gsum = (float*)alloc(NGRAPH * DDIM * sizeof(float));
  int* gcnt   = (int*)alloc(NGRAPH * sizeof(int));
  int* bsum   = (int*)alloc(NSCANB * sizeof(int));
  int* boffs  = (int*)alloc(NSCANB * sizeof(int));

  // CSR head: partitioned hist -> scans
  hipMemsetAsync(cnt, 0, NNODES * sizeof(int), stream);
  k_hist<<<HISTB8, 256, 0, stream>>>(edst, cnt);
  k_scan1<<<NSCANB, 256, 0, stream>>>(cnt, bsum);
  k_scan2<<<1, 256, 0, stream>>>(bsum, boffs);
  k_scan3<<<NSCANB + 2, 256, 0, stream>>>(cnt, boffs, rowptr, cursor,
                                          gsum, batch, gcnt);
  // fill (partitioned, prescaled col) || cvt_x || cvt_w
  k_fillcvt<<<HISTB8 + CVTXB + CVTWB, 256, 0, stream>>>(esrc, edst, cursor, col,
                                                        x, xb, W1l, W1r, W2l, W2r,
                                                        WT1, WT2);

  int ggrid = (NNODES + 127) / 128;
  int agg_grid = ((NNODES + 63) / 64) * 8;

  // layer 1
  k_agg<<<agg_grid, 256, 0, stream>>>(xb, rowptr, col, aggb);
  k_gemm<<<ggrid, 512, 0, stream>>>(aggb, xb, WT1, b1, h1b);

  // layer 2
  k_agg<<<agg_grid, 256, 0, stream>>>(h1b, rowptr, col, aggb);
  k_gemm<<<ggrid, 512, 0, stream>>>(aggb, h1b, WT2, b2, xb);

  // pool + classifier
  k_gsum<<<GSUM_WAVES / 4, 256, 0, stream>>>(xb, batch, gsum);
  k_cls<<<NGRAPH, 256, 0, stream>>>(gsum, gcnt, Wc, bc, out);
}